// Round 4
// baseline (932.319 us; speedup 1.0000x reference)
//
#include <hip/hip_runtime.h>
#include <cstdint>
#include <cstddef>

#define T_TOK 2048
#define DHID  2048
#define NEXP  8
#define FMOE  1408
#define FSH   2816
#define CAP   5120   // 4096 slots + 8*127 per-expert padding fits

// counted vmcnt wait (T4) — literal N required
#define WAITCNT_VM(N) asm volatile("s_waitcnt vmcnt(" #N ")" ::: "memory")

typedef short short8 __attribute__((ext_vector_type(8)));
typedef short short4v __attribute__((ext_vector_type(4)));
typedef float f32x4  __attribute__((ext_vector_type(4)));

__device__ __forceinline__ float bf2f(short s) {
  unsigned u = ((unsigned)(unsigned short)s) << 16;
  return __builtin_bit_cast(float, u);
}
__device__ __forceinline__ short f2bf(float f) {
  unsigned u = __builtin_bit_cast(unsigned, f);
  u += 0x7fffu + ((u >> 16) & 1u);
  return (short)(u >> 16);
}
__device__ __forceinline__ short8 cvt8(float4 a, float4 b) {
  short8 r;
  r[0]=f2bf(a.x); r[1]=f2bf(a.y); r[2]=f2bf(a.z); r[3]=f2bf(a.w);
  r[4]=f2bf(b.x); r[5]=f2bf(b.y); r[6]=f2bf(b.z); r[7]=f2bf(b.w);
  return r;
}

__device__ __forceinline__ void gl_lds16(const void* g, void* l) {
  __builtin_amdgcn_global_load_lds(
      (const __attribute__((address_space(1))) void*)g,
      (__attribute__((address_space(3))) void*)l, 16, 0, 0);
}

// ---- in-place fp32 -> bf16: row of len floats -> len bf16 in first half ----
__global__ void k_cvt(float* __restrict__ swg, float* __restrict__ swu,
                      float* __restrict__ swd, float* __restrict__ ewg,
                      float* __restrict__ ewu, float* __restrict__ ewd)
{
  int id = blockIdx.x;
  float* base; int row, len;
  if      (id < 2816)  { base = swg; row = id;          len = 2048; }
  else if (id < 5632)  { base = swu; row = id - 2816;   len = 2048; }
  else if (id < 7680)  { base = swd; row = id - 5632;   len = 2816; }
  else if (id < 18944) { base = ewg; row = id - 7680;   len = 2048; }
  else if (id < 30208) { base = ewu; row = id - 18944;  len = 2048; }
  else                 { base = ewd; row = id - 30208;  len = 1408; }
  float* rp = base + (size_t)row * len;
  int t = threadIdx.x, len4 = len >> 2;
  float4 v[3]; int cnt = 0;
  for (int i = t; i < len4; i += 256) v[cnt++] = ((const float4*)rp)[i];
  __syncthreads();
  short* sp = (short*)rp;
  cnt = 0;
  for (int i = t; i < len4; i += 256) {
    float4 f = v[cnt++];
    short4v s; s[0]=f2bf(f.x); s[1]=f2bf(f.y); s[2]=f2bf(f.z); s[3]=f2bf(f.w);
    ((short4v*)sp)[i] = s;
  }
}

// ---- gating: fp32 scores, sigmoid, top-2, counts; also write x as bf16 ----
__global__ void k_gate(const float* __restrict__ x, const float* __restrict__ gw,
                       int* __restrict__ top_idx, float* __restrict__ top_w,
                       int* __restrict__ ctrl, short* __restrict__ x16)
{
  int t = blockIdx.x, tid = threadIdx.x;
  const float* xr = x + (size_t)t * DHID + tid * 8;
  float4 v0 = *(const float4*)xr;
  float4 v1 = *(const float4*)(xr + 4);
  *(short8*)(x16 + (size_t)t * DHID + tid * 8) = cvt8(v0, v1);

  float s[NEXP];
  #pragma unroll
  for (int e = 0; e < NEXP; e++) {
    const float* gr = gw + e * DHID + tid * 8;
    float4 g0 = *(const float4*)gr;
    float4 g1 = *(const float4*)(gr + 4);
    s[e] = v0.x*g0.x + v0.y*g0.y + v0.z*g0.z + v0.w*g0.w
         + v1.x*g1.x + v1.y*g1.y + v1.z*g1.z + v1.w*g1.w;
  }
  #pragma unroll
  for (int e = 0; e < NEXP; e++)
    #pragma unroll
    for (int off = 32; off > 0; off >>= 1)
      s[e] += __shfl_xor(s[e], off);

  __shared__ float red[4][NEXP];
  int lane = tid & 63, wave = tid >> 6;
  if (lane == 0)
    for (int e = 0; e < NEXP; e++) red[wave][e] = s[e];
  __syncthreads();

  if (tid == 0) {
    float sc[NEXP];
    for (int e = 0; e < NEXP; e++) {
      float v = red[0][e] + red[1][e] + red[2][e] + red[3][e];
      sc[e] = 1.f / (1.f + __expf(-v));
    }
    int i0 = 0; float s0 = sc[0];
    for (int e = 1; e < NEXP; e++) if (sc[e] > s0) { s0 = sc[e]; i0 = e; }
    int i1 = -1; float s1 = -1e30f;
    for (int e = 0; e < NEXP; e++) if (e != i0 && sc[e] > s1) { s1 = sc[e]; i1 = e; }
    float inv = 2.5f / (s0 + s1 + 1e-20f);
    top_idx[2*t] = i0; top_idx[2*t+1] = i1;
    top_w[2*t] = s0 * inv; top_w[2*t+1] = s1 * inv;
    atomicAdd(&ctrl[i0], 1);
    atomicAdd(&ctrl[i1], 1);
  }
}

// ---- offsets + flat-work prefix tables ----
__global__ void k_offsets(int* __restrict__ ctrl)
{
  if (blockIdx.x == 0 && threadIdx.x == 0) {
    int cum = 0, gp = 0, dp = 0;
    ctrl[24] = 0; ctrl[40] = 0;
    for (int e = 0; e < NEXP; e++) {
      ctrl[16 + e] = cum;
      int mb = (ctrl[e] + 127) >> 7;
      cum += mb << 7;
      gp += mb * (FMOE / 128); ctrl[25 + e] = gp;
      dp += mb * (DHID / 128); ctrl[41 + e] = dp;
    }
    ctrl[33] = gp + (T_TOK / 128) * (FSH / 128);   // + shared 16*22
    ctrl[49] = dp + (T_TOK / 128) * (DHID / 128);  // + shared 16*16
  }
}

// ---- slot maps ----
__global__ void k_slotmap(const int* __restrict__ top_idx, int* __restrict__ ctrl,
                          int* __restrict__ tok_row, int* __restrict__ slot2tok)
{
  int i = blockIdx.x * 256 + threadIdx.x;
  if (i >= 2 * T_TOK) return;
  int e = top_idx[i];
  int slot = atomicAdd(&ctrl[8 + e], 1);
  int row = ctrl[16 + e] + slot;
  tok_row[i] = row;
  slot2tok[row] = i >> 1;
}

// ---- flat fused gate/up GEMM + SiLU ----
// 3-deep LDS pipeline, ONE raw s_barrier per K-step, counted vmcnt(6):
// stage(t) completion is guaranteed by each wave's own vmcnt wait before the
// barrier; stage(t+2) overwrites buf (t-1)%3, whose readers all finished
// compute(t-1) before this barrier. Loads get 2 K-steps to land; never drain.
__global__ __launch_bounds__(256) void k_guf(
    const short* __restrict__ x16,
    const short* __restrict__ ewg, const short* __restrict__ ewu,
    const short* __restrict__ swg, const short* __restrict__ swu,
    short* __restrict__ Hx, short* __restrict__ Hs,
    const int* __restrict__ ctrl, const int* __restrict__ slot2tok)
{
  int W = ctrl[33];
  int b = blockIdx.x;
  if (b >= W) return;
  // bijective chunked XCD swizzle (m204): same-B blocks stay on one XCD
  int cq = W >> 3, cr = W & 7, xcd = b & 7, li = b >> 3;
  int flat = (xcd < cr ? xcd * (cq + 1) : cr * (cq + 1) + (xcd - cr) * cq) + li;

  int z = 0;
  while (flat >= ctrl[25 + z]) z++;
  int w = flat - ctrl[24 + z];

  int tid = threadIdx.x;
  int r = tid >> 2, sl = (tid & 3) * 8;

  const short *Bg, *Bu; short* H; int N;
  int tokr0, tokr1; size_t hrow0;
  if (z == 8) {
    // m-fastest: consecutive blocks share the B panel (weights = big stream)
    int my = w & 15, nx = w >> 4;
    int n0v = nx * 128;
    N = FSH; H = Hs; Bg = swg + (size_t)n0v * (2 * DHID); Bu = swu + (size_t)n0v * (2 * DHID);
    int m0 = my * 128;
    tokr0 = m0 + r; tokr1 = m0 + r + 64;
    hrow0 = m0;
    w = n0v;               // reuse w as n0
  } else {
    int mb = (ctrl[z] + 127) >> 7;
    int my = w % mb, nx = w / mb;
    int n0v = nx * 128;
    N = FMOE; H = Hx;
    size_t woff = (size_t)z * FMOE * (2 * DHID);
    Bg = ewg + woff + (size_t)n0v * (2 * DHID);
    Bu = ewu + woff + (size_t)n0v * (2 * DHID);
    int cnt = ctrl[z], base = ctrl[16 + z];
    int m0 = my * 128;
    int rr0 = m0 + r, rr1 = m0 + r + 64;
    tokr0 = (rr0 < cnt) ? slot2tok[base + rr0] : 0;
    tokr1 = (rr1 < cnt) ? slot2tok[base + rr1] : 0;
    hrow0 = base + m0;
    w = n0v;               // reuse w as n0
  }
  int n0 = w;

  __shared__ short As [3][128 * 32];
  __shared__ short Bgs[3][128 * 32];
  __shared__ short Bus[3][128 * 32];

  int lane = tid & 63, wave = tid >> 6;
  int l15 = lane & 15, qh = lane >> 4;
  int wm = (wave >> 1) * 64, wn = (wave & 1) * 64;

  f32x4 z4 = {0.f, 0.f, 0.f, 0.f};
  f32x4 accg[4][4], accu[4][4];
  #pragma unroll
  for (int a = 0; a < 4; a++)
    #pragma unroll
    for (int c = 0; c < 4; c++) { accg[a][c] = z4; accu[a][c] = z4; }

  const short* Ag0 = x16 + (size_t)tokr0 * DHID + sl;
  const short* Ag1 = x16 + (size_t)tokr1 * DHID + sl;
  const short* Bgp0 = Bg + (size_t)r * (2 * DHID) + sl;
  const short* Bgp1 = Bgp0 + (size_t)64 * (2 * DHID);
  const short* Bup0 = Bu + (size_t)r * (2 * DHID) + sl;
  const short* Bup1 = Bup0 + (size_t)64 * (2 * DHID);

  auto stage = [&](int bi, int k0) {
    gl_lds16(Ag0  + k0, &As [bi][tid * 8]);
    gl_lds16(Ag1  + k0, &As [bi][tid * 8 + 2048]);
    gl_lds16(Bgp0 + k0, &Bgs[bi][tid * 8]);
    gl_lds16(Bgp1 + k0, &Bgs[bi][tid * 8 + 2048]);
    gl_lds16(Bup0 + k0, &Bus[bi][tid * 8]);
    gl_lds16(Bup1 + k0, &Bus[bi][tid * 8 + 2048]);
  };
  auto compute = [&](int bi) {
    short8 af[4], bg[4], bu[4];
    #pragma unroll
    for (int mi = 0; mi < 4; mi++)
      af[mi] = *(const short8*)&As[bi][(wm + mi * 16 + l15) * 32 + qh * 8];
    #pragma unroll
    for (int ni = 0; ni < 4; ni++) {
      bg[ni] = *(const short8*)&Bgs[bi][(wn + ni * 16 + l15) * 32 + qh * 8];
      bu[ni] = *(const short8*)&Bus[bi][(wn + ni * 16 + l15) * 32 + qh * 8];
    }
    #pragma unroll
    for (int mi = 0; mi < 4; mi++)
      #pragma unroll
      for (int ni = 0; ni < 4; ni++) {
        accg[mi][ni] = __builtin_amdgcn_mfma_f32_16x16x32_bf16(af[mi], bg[ni], accg[mi][ni], 0, 0, 0);
        accu[mi][ni] = __builtin_amdgcn_mfma_f32_16x16x32_bf16(af[mi], bu[ni], accu[mi][ni], 0, 0, 0);
      }
  };

  // 3-deep pipeline, 64 K-steps
  stage(0, 0);
  stage(1, 32);
  int bi = 0;
  for (int t = 0; t < 64; ++t) {
    if (t < 63) { WAITCNT_VM(6); } else { WAITCNT_VM(0); }
    __builtin_amdgcn_s_barrier();
    if (t < 62) {
      int bi2 = bi + 2; if (bi2 >= 3) bi2 -= 3;
      stage(bi2, (t + 2) * 32);
    }
    compute(bi);
    ++bi; if (bi == 3) bi = 0;
  }

  // epilogue: D row = qh*4 + reg, col = l15  [measured m89/m91]
  #pragma unroll
  for (int mi = 0; mi < 4; mi++) {
    #pragma unroll
    for (int rg = 0; rg < 4; rg++) {
      size_t row = hrow0 + wm + mi * 16 + qh * 4 + rg;
      size_t baseo = row * (size_t)N + n0 + wn + l15;
      #pragma unroll
      for (int ni = 0; ni < 4; ni++) {
        float g = accg[mi][ni][rg];
        float u = accu[mi][ni][rg];
        H[baseo + ni * 16] = f2bf((g / (1.f + __expf(-g))) * u);
      }
    }
  }
}

// ---- flat down GEMM: C[*,2048] = H[*,K] @ Wd[2048,K]^T, same pipeline ----
__global__ __launch_bounds__(256) void k_down(
    const short* __restrict__ Hx, const short* __restrict__ Hs,
    const short* __restrict__ ewd, const short* __restrict__ swd,
    short* __restrict__ rout, float* __restrict__ out,
    const int* __restrict__ ctrl)
{
  int W = ctrl[49];
  int b = blockIdx.x;
  if (b >= W) return;
  int cq = W >> 3, cr = W & 7, xcd = b & 7, li = b >> 3;
  int flat = (xcd < cr ? xcd * (cq + 1) : cr * (cq + 1) + (xcd - cr) * cq) + li;

  int z = 0;
  while (flat >= ctrl[41 + z]) z++;
  int w = flat - ctrl[40 + z];

  const short *A, *B; int K; size_t crow0;
  int my, n0;
  if (z == 8) {
    my = w & 15; n0 = (w >> 4) * 128;
    A = Hs + (size_t)(my * 128) * FSH; B = swd; K = FSH;
    crow0 = my * 128;
  } else {
    int mb = (ctrl[z] + 127) >> 7;
    my = w % mb; n0 = (w / mb) * 128;
    int base = ctrl[16 + z];
    A = Hx + (size_t)(base + my * 128) * FMOE;
    B = ewd + (size_t)z * DHID * (2 * FMOE); K = FMOE;
    crow0 = base + my * 128;
  }

  __shared__ short As[3][128 * 32];
  __shared__ short Bs[3][128 * 32];

  int tid = threadIdx.x;
  int lane = tid & 63, wave = tid >> 6;
  int l15 = lane & 15, qh = lane >> 4;
  int wm = (wave >> 1) * 64, wn = (wave & 1) * 64;

  f32x4 z4 = {0.f, 0.f, 0.f, 0.f};
  f32x4 acc[4][4];
  #pragma unroll
  for (int a = 0; a < 4; a++)
    #pragma unroll
    for (int c = 0; c < 4; c++) acc[a][c] = z4;

  int r = tid >> 2, sl = (tid & 3) * 8;
  const short* Ag0 = A + (size_t)r * K + sl;
  const short* Ag1 = Ag0 + (size_t)64 * K;
  const short* Bp0 = B + (size_t)(n0 + r) * (2 * K) + sl;
  const short* Bp1 = Bp0 + (size_t)64 * (2 * K);

  auto stage = [&](int bi, int k0) {
    gl_lds16(Ag0 + k0, &As[bi][tid * 8]);
    gl_lds16(Ag1 + k0, &As[bi][tid * 8 + 2048]);
    gl_lds16(Bp0 + k0, &Bs[bi][tid * 8]);
    gl_lds16(Bp1 + k0, &Bs[bi][tid * 8 + 2048]);
  };
  auto compute = [&](int bi) {
    short8 af[4], bf[4];
    #pragma unroll
    for (int mi = 0; mi < 4; mi++)
      af[mi] = *(const short8*)&As[bi][(wm + mi * 16 + l15) * 32 + qh * 8];
    #pragma unroll
    for (int ni = 0; ni < 4; ni++)
      bf[ni] = *(const short8*)&Bs[bi][(wn + ni * 16 + l15) * 32 + qh * 8];
    #pragma unroll
    for (int mi = 0; mi < 4; mi++)
      #pragma unroll
      for (int ni = 0; ni < 4; ni++)
        acc[mi][ni] = __builtin_amdgcn_mfma_f32_16x16x32_bf16(af[mi], bf[ni], acc[mi][ni], 0, 0, 0);
  };

  int nt = K >> 5;          // 44 (expert) or 88 (shared)
  stage(0, 0);
  stage(1, 32);
  int bi = 0;
  for (int t = 0; t < nt; ++t) {
    if (t < nt - 1) { WAITCNT_VM(6); } else { WAITCNT_VM(0); }
    __builtin_amdgcn_s_barrier();
    if (t + 2 < nt) {
      int bi2 = bi + 2; if (bi2 >= 3) bi2 -= 3;
      stage(bi2, (t + 2) * 32);
    }
    compute(bi);
    ++bi; if (bi == 3) bi = 0;
  }

  #pragma unroll
  for (int mi = 0; mi < 4; mi++) {
    #pragma unroll
    for (int rg = 0; rg < 4; rg++) {
      size_t row = crow0 + wm + mi * 16 + qh * 4 + rg;
      size_t baseo = row * (size_t)DHID + n0 + wn + l15;
      #pragma unroll
      for (int ni = 0; ni < 4; ni++) {
        float v = acc[mi][ni][rg];
        if (z == 8) out[baseo + ni * 16] = v;
        else        rout[baseo + ni * 16] = f2bf(v);
      }
    }
  }
}

// ---- out += w0*routed[row0] + w1*routed[row1] ----
__global__ void k_add(float* __restrict__ out, const short* __restrict__ rout,
                      const int* __restrict__ tok_row, const float* __restrict__ top_w)
{
  int t = blockIdx.x, tid = threadIdx.x;
  int r0 = tok_row[2*t], r1 = tok_row[2*t+1];
  float w0 = top_w[2*t], w1 = top_w[2*t+1];
  size_t c = (size_t)tid * 8;
  short8 a = *(const short8*)(rout + (size_t)r0 * DHID + c);
  short8 b = *(const short8*)(rout + (size_t)r1 * DHID + c);
  float* o = out + (size_t)t * DHID + c;
  float4 o0 = *(float4*)o;
  float4 o1 = *(float4*)(o + 4);
  o0.x += w0*bf2f(a[0]) + w1*bf2f(b[0]);
  o0.y += w0*bf2f(a[1]) + w1*bf2f(b[1]);
  o0.z += w0*bf2f(a[2]) + w1*bf2f(b[2]);
  o0.w += w0*bf2f(a[3]) + w1*bf2f(b[3]);
  o1.x += w0*bf2f(a[4]) + w1*bf2f(b[4]);
  o1.y += w0*bf2f(a[5]) + w1*bf2f(b[5]);
  o1.z += w0*bf2f(a[6]) + w1*bf2f(b[6]);
  o1.w += w0*bf2f(a[7]) + w1*bf2f(b[7]);
  *(float4*)o = o0;
  *(float4*)(o + 4) = o1;
}

extern "C" void kernel_launch(void* const* d_in, const int* in_sizes, int n_in,
                              void* d_out, int out_size, void* d_ws, size_t ws_size,
                              hipStream_t stream)
{
  const float* x  = (const float*)d_in[0];
  const float* gw = (const float*)d_in[1];
  float* swg = (float*)d_in[2];
  float* swu = (float*)d_in[3];
  float* swd = (float*)d_in[4];
  float* ewg = (float*)d_in[5];
  float* ewu = (float*)d_in[6];
  float* ewd = (float*)d_in[7];
  float* out = (float*)d_out;

  char* p = (char*)d_ws;
  int*   ctrl     = (int*)p;   p += 256;
  int*   top_idx  = (int*)p;   p += T_TOK * 2 * sizeof(int);
  float* top_w    = (float*)p; p += T_TOK * 2 * sizeof(float);
  int*   tok_row  = (int*)p;   p += T_TOK * 2 * sizeof(int);
  int*   slot2tok = (int*)p;   p += CAP * sizeof(int);
  short* x16  = (short*)p;     p += (size_t)T_TOK * DHID * 2;
  short* Hx   = (short*)p;     p += (size_t)CAP * FMOE * 2;
  short* Hs   = (short*)p;     p += (size_t)T_TOK * FSH * 2;
  short* rout = (short*)p;     p += (size_t)CAP * DHID * 2;

  (void)hipMemsetAsync(ctrl, 0, 64, stream);

  k_gate<<<T_TOK, 256, 0, stream>>>(x, gw, top_idx, top_w, ctrl, x16);
  k_offsets<<<1, 64, 0, stream>>>(ctrl);
  k_slotmap<<<(2 * T_TOK + 255) / 256, 256, 0, stream>>>(top_idx, ctrl, tok_row, slot2tok);
  k_cvt<<<46592, 256, 0, stream>>>(swg, swu, swd, ewg, ewu, ewd);

  k_guf<<<784, 256, 0, stream>>>(
      x16, (const short*)ewg, (const short*)ewu,
      (const short*)swg, (const short*)swu, Hx, Hs, ctrl, slot2tok);

  k_down<<<880, 256, 0, stream>>>(
      Hx, Hs, (const short*)ewd, (const short*)swd, rout, out, ctrl);

  k_add<<<T_TOK, 256, 0, stream>>>(out, rout, tok_row, top_w);
}

// Round 5
// 732.880 us; speedup vs baseline: 1.2721x; 1.2721x over previous
//
#include <hip/hip_runtime.h>
#include <cstdint>
#include <cstddef>

#define T_TOK 2048
#define DHID  2048
#define NEXP  8
#define FMOE  1408
#define FSH   2816
#define CAP   5120   // 4096 slots + 8*127 per-expert padding fits

typedef short short8 __attribute__((ext_vector_type(8)));
typedef short short4v __attribute__((ext_vector_type(4)));
typedef float f32x4  __attribute__((ext_vector_type(4)));

__device__ __forceinline__ float bf2f(short s) {
  unsigned u = ((unsigned)(unsigned short)s) << 16;
  return __builtin_bit_cast(float, u);
}
__device__ __forceinline__ short f2bf(float f) {
  unsigned u = __builtin_bit_cast(unsigned, f);
  u += 0x7fffu + ((u >> 16) & 1u);
  return (short)(u >> 16);
}
__device__ __forceinline__ short8 cvt8(float4 a, float4 b) {
  short8 r;
  r[0]=f2bf(a.x); r[1]=f2bf(a.y); r[2]=f2bf(a.z); r[3]=f2bf(a.w);
  r[4]=f2bf(b.x); r[5]=f2bf(b.y); r[6]=f2bf(b.z); r[7]=f2bf(b.w);
  return r;
}

__device__ __forceinline__ void gl_lds16(const void* g, void* l) {
  __builtin_amdgcn_global_load_lds(
      (const __attribute__((address_space(1))) void*)g,
      (__attribute__((address_space(3))) void*)l, 16, 0, 0);
}

// ---- in-place fp32 -> bf16: row of len floats -> len bf16 in first half ----
__global__ void k_cvt(float* __restrict__ swg, float* __restrict__ swu,
                      float* __restrict__ swd, float* __restrict__ ewg,
                      float* __restrict__ ewu, float* __restrict__ ewd)
{
  int id = blockIdx.x;
  float* base; int row, len;
  if      (id < 2816)  { base = swg; row = id;          len = 2048; }
  else if (id < 5632)  { base = swu; row = id - 2816;   len = 2048; }
  else if (id < 7680)  { base = swd; row = id - 5632;   len = 2816; }
  else if (id < 18944) { base = ewg; row = id - 7680;   len = 2048; }
  else if (id < 30208) { base = ewu; row = id - 18944;  len = 2048; }
  else                 { base = ewd; row = id - 30208;  len = 1408; }
  float* rp = base + (size_t)row * len;
  int t = threadIdx.x, len4 = len >> 2;
  float4 v[3]; int cnt = 0;
  for (int i = t; i < len4; i += 256) v[cnt++] = ((const float4*)rp)[i];
  __syncthreads();
  short* sp = (short*)rp;
  cnt = 0;
  for (int i = t; i < len4; i += 256) {
    float4 f = v[cnt++];
    short4v s; s[0]=f2bf(f.x); s[1]=f2bf(f.y); s[2]=f2bf(f.z); s[3]=f2bf(f.w);
    ((short4v*)sp)[i] = s;
  }
}

// ---- gating: fp32 scores, sigmoid, top-2, counts; also write x as bf16 ----
__global__ void k_gate(const float* __restrict__ x, const float* __restrict__ gw,
                       int* __restrict__ top_idx, float* __restrict__ top_w,
                       int* __restrict__ ctrl, short* __restrict__ x16)
{
  int t = blockIdx.x, tid = threadIdx.x;
  const float* xr = x + (size_t)t * DHID + tid * 8;
  float4 v0 = *(const float4*)xr;
  float4 v1 = *(const float4*)(xr + 4);
  *(short8*)(x16 + (size_t)t * DHID + tid * 8) = cvt8(v0, v1);

  float s[NEXP];
  #pragma unroll
  for (int e = 0; e < NEXP; e++) {
    const float* gr = gw + e * DHID + tid * 8;
    float4 g0 = *(const float4*)gr;
    float4 g1 = *(const float4*)(gr + 4);
    s[e] = v0.x*g0.x + v0.y*g0.y + v0.z*g0.z + v0.w*g0.w
         + v1.x*g1.x + v1.y*g1.y + v1.z*g1.z + v1.w*g1.w;
  }
  #pragma unroll
  for (int e = 0; e < NEXP; e++)
    #pragma unroll
    for (int off = 32; off > 0; off >>= 1)
      s[e] += __shfl_xor(s[e], off);

  __shared__ float red[4][NEXP];
  int lane = tid & 63, wave = tid >> 6;
  if (lane == 0)
    for (int e = 0; e < NEXP; e++) red[wave][e] = s[e];
  __syncthreads();

  if (tid == 0) {
    float sc[NEXP];
    for (int e = 0; e < NEXP; e++) {
      float v = red[0][e] + red[1][e] + red[2][e] + red[3][e];
      sc[e] = 1.f / (1.f + __expf(-v));
    }
    int i0 = 0; float s0 = sc[0];
    for (int e = 1; e < NEXP; e++) if (sc[e] > s0) { s0 = sc[e]; i0 = e; }
    int i1 = -1; float s1 = -1e30f;
    for (int e = 0; e < NEXP; e++) if (e != i0 && sc[e] > s1) { s1 = sc[e]; i1 = e; }
    float inv = 2.5f / (s0 + s1 + 1e-20f);
    top_idx[2*t] = i0; top_idx[2*t+1] = i1;
    top_w[2*t] = s0 * inv; top_w[2*t+1] = s1 * inv;
    atomicAdd(&ctrl[i0], 1);
    atomicAdd(&ctrl[i1], 1);
  }
}

// ---- offsets + flat-work prefix tables (BN=64 tiles) ----
__global__ void k_offsets(int* __restrict__ ctrl)
{
  if (blockIdx.x == 0 && threadIdx.x == 0) {
    int cum = 0, gp = 0, dp = 0;
    ctrl[24] = 0; ctrl[40] = 0;
    for (int e = 0; e < NEXP; e++) {
      ctrl[16 + e] = cum;
      int mb = (ctrl[e] + 127) >> 7;
      cum += mb << 7;
      gp += mb * (FMOE / 64); ctrl[25 + e] = gp;
      dp += mb * (DHID / 64); ctrl[41 + e] = dp;
    }
    ctrl[33] = gp + (T_TOK / 128) * (FSH / 64);    // + shared 16*44
    ctrl[49] = dp + (T_TOK / 128) * (DHID / 64);   // + shared 16*32
  }
}

// ---- slot maps ----
__global__ void k_slotmap(const int* __restrict__ top_idx, int* __restrict__ ctrl,
                          int* __restrict__ tok_row, int* __restrict__ slot2tok)
{
  int i = blockIdx.x * 256 + threadIdx.x;
  if (i >= 2 * T_TOK) return;
  int e = top_idx[i];
  int slot = atomicAdd(&ctrl[8 + e], 1);
  int row = ctrl[16 + e] + slot;
  tok_row[i] = row;
  slot2tok[row] = i >> 1;
}

// ---- flat fused gate/up GEMM + SiLU, 128x64 tile, 2-deep dbuf ----
// r3/r4 A/B showed throughput ~ resident blocks/CU (latency-bound, TLP-hidden).
// BN=64: grid ~1584 (~6/CU), LDS 32KB (5 blocks), acc halves -> VGPR ~120;
// launch_bounds(256,4) caps at 128 (above demand; r1 lesson: never cap below).
__global__ __launch_bounds__(256, 4) void k_guf(
    const short* __restrict__ x16,
    const short* __restrict__ ewg, const short* __restrict__ ewu,
    const short* __restrict__ swg, const short* __restrict__ swu,
    short* __restrict__ Hx, short* __restrict__ Hs,
    const int* __restrict__ ctrl, const int* __restrict__ slot2tok)
{
  int W = ctrl[33];
  int b = blockIdx.x;
  if (b >= W) return;
  // bijective chunked XCD swizzle (m204)
  int cq = W >> 3, cr = W & 7, xcd = b & 7, li = b >> 3;
  int flat = (xcd < cr ? xcd * (cq + 1) : cr * (cq + 1) + (xcd - cr) * cq) + li;

  int z = 0;
  while (flat >= ctrl[25 + z]) z++;
  int w = flat - ctrl[24 + z];

  int tid = threadIdx.x;
  int r = tid >> 2, sl = (tid & 3) * 8;

  const short *Bg, *Bu; short* H; int N;
  int tokr0, tokr1; size_t hrow0;
  if (z == 8) {
    // m-fastest: consecutive blocks share the B panel
    int my = w & 15, nx = w >> 4;
    int n0v = nx * 64;
    N = FSH; H = Hs; Bg = swg + (size_t)n0v * (2 * DHID); Bu = swu + (size_t)n0v * (2 * DHID);
    int m0 = my * 128;
    tokr0 = m0 + r; tokr1 = m0 + r + 64;
    hrow0 = m0;
    w = n0v;
  } else {
    int mb = (ctrl[z] + 127) >> 7;
    int my = w % mb, nx = w / mb;
    int n0v = nx * 64;
    N = FMOE; H = Hx;
    size_t woff = (size_t)z * FMOE * (2 * DHID);
    Bg = ewg + woff + (size_t)n0v * (2 * DHID);
    Bu = ewu + woff + (size_t)n0v * (2 * DHID);
    int cnt = ctrl[z], base = ctrl[16 + z];
    int m0 = my * 128;
    int rr0 = m0 + r, rr1 = m0 + r + 64;
    tokr0 = (rr0 < cnt) ? slot2tok[base + rr0] : 0;
    tokr1 = (rr1 < cnt) ? slot2tok[base + rr1] : 0;
    hrow0 = base + m0;
    w = n0v;
  }
  int n0 = w;

  __shared__ short As [2][128 * 32];   // 16 KB
  __shared__ short Bgs[2][64 * 32];    //  8 KB
  __shared__ short Bus[2][64 * 32];    //  8 KB

  int lane = tid & 63, wave = tid >> 6;
  int l15 = lane & 15, qh = lane >> 4;
  int wm = (wave >> 1) * 64, wn = (wave & 1) * 32;

  f32x4 z4 = {0.f, 0.f, 0.f, 0.f};
  f32x4 accg[4][2], accu[4][2];
  #pragma unroll
  for (int a = 0; a < 4; a++)
    #pragma unroll
    for (int c = 0; c < 2; c++) { accg[a][c] = z4; accu[a][c] = z4; }

  const short* Ag0 = x16 + (size_t)tokr0 * DHID + sl;
  const short* Ag1 = x16 + (size_t)tokr1 * DHID + sl;
  const short* Bgp = Bg + (size_t)r * (2 * DHID) + sl;   // r = 0..63 rows
  const short* Bup = Bu + (size_t)r * (2 * DHID) + sl;

  auto stage = [&](int bi, int k0) {
    gl_lds16(Ag0 + k0, &As [bi][tid * 8]);
    gl_lds16(Ag1 + k0, &As [bi][tid * 8 + 2048]);
    gl_lds16(Bgp + k0, &Bgs[bi][tid * 8]);
    gl_lds16(Bup + k0, &Bus[bi][tid * 8]);
  };
  auto compute = [&](int bi) {
    short8 af[4], bg[2], bu[2];
    #pragma unroll
    for (int mi = 0; mi < 4; mi++)
      af[mi] = *(const short8*)&As[bi][(wm + mi * 16 + l15) * 32 + qh * 8];
    #pragma unroll
    for (int ni = 0; ni < 2; ni++) {
      bg[ni] = *(const short8*)&Bgs[bi][(wn + ni * 16 + l15) * 32 + qh * 8];
      bu[ni] = *(const short8*)&Bus[bi][(wn + ni * 16 + l15) * 32 + qh * 8];
    }
    #pragma unroll
    for (int mi = 0; mi < 4; mi++)
      #pragma unroll
      for (int ni = 0; ni < 2; ni++) {
        accg[mi][ni] = __builtin_amdgcn_mfma_f32_16x16x32_bf16(af[mi], bg[ni], accg[mi][ni], 0, 0, 0);
        accu[mi][ni] = __builtin_amdgcn_mfma_f32_16x16x32_bf16(af[mi], bu[ni], accu[mi][ni], 0, 0, 0);
      }
  };

  stage(0, 0);
  __syncthreads();
  int cur = 0;
  for (int k0 = 32; k0 < DHID; k0 += 32) {
    stage(cur ^ 1, k0);
    compute(cur);
    __syncthreads();
    cur ^= 1;
  }
  compute(cur);

  // epilogue: D row = qh*4 + reg, col = l15  [measured m89/m91]
  #pragma unroll
  for (int mi = 0; mi < 4; mi++) {
    #pragma unroll
    for (int rg = 0; rg < 4; rg++) {
      size_t row = hrow0 + wm + mi * 16 + qh * 4 + rg;
      size_t baseo = row * (size_t)N + n0 + wn + l15;
      #pragma unroll
      for (int ni = 0; ni < 2; ni++) {
        float g = accg[mi][ni][rg];
        float u = accu[mi][ni][rg];
        H[baseo + ni * 16] = f2bf((g / (1.f + __expf(-g))) * u);
      }
    }
  }
}

// ---- flat down GEMM: C[*,2048] = H[*,K] @ Wd[2048,K]^T, 128x64 tile ----
__global__ __launch_bounds__(256, 4) void k_down(
    const short* __restrict__ Hx, const short* __restrict__ Hs,
    const short* __restrict__ ewd, const short* __restrict__ swd,
    short* __restrict__ rout, float* __restrict__ out,
    const int* __restrict__ ctrl)
{
  int W = ctrl[49];
  int b = blockIdx.x;
  if (b >= W) return;
  int cq = W >> 3, cr = W & 7, xcd = b & 7, li = b >> 3;
  int flat = (xcd < cr ? xcd * (cq + 1) : cr * (cq + 1) + (xcd - cr) * cq) + li;

  int z = 0;
  while (flat >= ctrl[41 + z]) z++;
  int w = flat - ctrl[40 + z];

  const short *A, *B; int K; size_t crow0;
  int my, n0;
  if (z == 8) {
    my = w & 15; n0 = (w >> 4) * 64;
    A = Hs + (size_t)(my * 128) * FSH; B = swd; K = FSH;
    crow0 = my * 128;
  } else {
    int mb = (ctrl[z] + 127) >> 7;
    my = w % mb; n0 = (w / mb) * 64;
    int base = ctrl[16 + z];
    A = Hx + (size_t)(base + my * 128) * FMOE;
    B = ewd + (size_t)z * DHID * (2 * FMOE); K = FMOE;
    crow0 = base + my * 128;
  }

  __shared__ short As[2][128 * 32];   // 16 KB
  __shared__ short Bs[2][64 * 32];    //  8 KB

  int tid = threadIdx.x;
  int lane = tid & 63, wave = tid >> 6;
  int l15 = lane & 15, qh = lane >> 4;
  int wm = (wave >> 1) * 64, wn = (wave & 1) * 32;

  f32x4 z4 = {0.f, 0.f, 0.f, 0.f};
  f32x4 acc[4][2];
  #pragma unroll
  for (int a = 0; a < 4; a++)
    #pragma unroll
    for (int c = 0; c < 2; c++) acc[a][c] = z4;

  int r = tid >> 2, sl = (tid & 3) * 8;
  const short* Ag0 = A + (size_t)r * K + sl;
  const short* Ag1 = Ag0 + (size_t)64 * K;
  const short* Bp  = B + (size_t)(n0 + r) * (2 * K) + sl;

  auto stage = [&](int bi, int k0) {
    gl_lds16(Ag0 + k0, &As[bi][tid * 8]);
    gl_lds16(Ag1 + k0, &As[bi][tid * 8 + 2048]);
    gl_lds16(Bp  + k0, &Bs[bi][tid * 8]);
  };
  auto compute = [&](int bi) {
    short8 af[4], bf[2];
    #pragma unroll
    for (int mi = 0; mi < 4; mi++)
      af[mi] = *(const short8*)&As[bi][(wm + mi * 16 + l15) * 32 + qh * 8];
    #pragma unroll
    for (int ni = 0; ni < 2; ni++)
      bf[ni] = *(const short8*)&Bs[bi][(wn + ni * 16 + l15) * 32 + qh * 8];
    #pragma unroll
    for (int mi = 0; mi < 4; mi++)
      #pragma unroll
      for (int ni = 0; ni < 2; ni++)
        acc[mi][ni] = __builtin_amdgcn_mfma_f32_16x16x32_bf16(af[mi], bf[ni], acc[mi][ni], 0, 0, 0);
  };

  stage(0, 0);
  __syncthreads();
  int cur = 0;
  for (int k0 = 32; k0 < K; k0 += 32) {
    stage(cur ^ 1, k0);
    compute(cur);
    __syncthreads();
    cur ^= 1;
  }
  compute(cur);

  #pragma unroll
  for (int mi = 0; mi < 4; mi++) {
    #pragma unroll
    for (int rg = 0; rg < 4; rg++) {
      size_t row = crow0 + wm + mi * 16 + qh * 4 + rg;
      size_t baseo = row * (size_t)DHID + n0 + wn + l15;
      #pragma unroll
      for (int ni = 0; ni < 2; ni++) {
        float v = acc[mi][ni][rg];
        if (z == 8) out[baseo + ni * 16] = v;
        else        rout[baseo + ni * 16] = f2bf(v);
      }
    }
  }
}

// ---- out += w0*routed[row0] + w1*routed[row1] ----
__global__ void k_add(float* __restrict__ out, const short* __restrict__ rout,
                      const int* __restrict__ tok_row, const float* __restrict__ top_w)
{
  int t = blockIdx.x, tid = threadIdx.x;
  int r0 = tok_row[2*t], r1 = tok_row[2*t+1];
  float w0 = top_w[2*t], w1 = top_w[2*t+1];
  size_t c = (size_t)tid * 8;
  short8 a = *(const short8*)(rout + (size_t)r0 * DHID + c);
  short8 b = *(const short8*)(rout + (size_t)r1 * DHID + c);
  float* o = out + (size_t)t * DHID + c;
  float4 o0 = *(float4*)o;
  float4 o1 = *(float4*)(o + 4);
  o0.x += w0*bf2f(a[0]) + w1*bf2f(b[0]);
  o0.y += w0*bf2f(a[1]) + w1*bf2f(b[1]);
  o0.z += w0*bf2f(a[2]) + w1*bf2f(b[2]);
  o0.w += w0*bf2f(a[3]) + w1*bf2f(b[3]);
  o1.x += w0*bf2f(a[4]) + w1*bf2f(b[4]);
  o1.y += w0*bf2f(a[5]) + w1*bf2f(b[5]);
  o1.z += w0*bf2f(a[6]) + w1*bf2f(b[6]);
  o1.w += w0*bf2f(a[7]) + w1*bf2f(b[7]);
  *(float4*)o = o0;
  *(float4*)(o + 4) = o1;
}

extern "C" void kernel_launch(void* const* d_in, const int* in_sizes, int n_in,
                              void* d_out, int out_size, void* d_ws, size_t ws_size,
                              hipStream_t stream)
{
  const float* x  = (const float*)d_in[0];
  const float* gw = (const float*)d_in[1];
  float* swg = (float*)d_in[2];
  float* swu = (float*)d_in[3];
  float* swd = (float*)d_in[4];
  float* ewg = (float*)d_in[5];
  float* ewu = (float*)d_in[6];
  float* ewd = (float*)d_in[7];
  float* out = (float*)d_out;

  char* p = (char*)d_ws;
  int*   ctrl     = (int*)p;   p += 256;
  int*   top_idx  = (int*)p;   p += T_TOK * 2 * sizeof(int);
  float* top_w    = (float*)p; p += T_TOK * 2 * sizeof(float);
  int*   tok_row  = (int*)p;   p += T_TOK * 2 * sizeof(int);
  int*   slot2tok = (int*)p;   p += CAP * sizeof(int);
  short* x16  = (short*)p;     p += (size_t)T_TOK * DHID * 2;
  short* Hx   = (short*)p;     p += (size_t)CAP * FMOE * 2;
  short* Hs   = (short*)p;     p += (size_t)T_TOK * FSH * 2;
  short* rout = (short*)p;     p += (size_t)CAP * DHID * 2;

  (void)hipMemsetAsync(ctrl, 0, 64, stream);

  k_gate<<<T_TOK, 256, 0, stream>>>(x, gw, top_idx, top_w, ctrl, x16);
  k_offsets<<<1, 64, 0, stream>>>(ctrl);
  k_slotmap<<<(2 * T_TOK + 255) / 256, 256, 0, stream>>>(top_idx, ctrl, tok_row, slot2tok);
  k_cvt<<<46592, 256, 0, stream>>>(swg, swu, swd, ewg, ewu, ewd);

  // worst-case grids: guf <= 40 m-tiles*22 + 16*44 = 1584; down <= 40*32 + 16*32 = 1792
  k_guf<<<1600, 256, 0, stream>>>(
      x16, (const short*)ewg, (const short*)ewu,
      (const short*)swg, (const short*)swu, Hx, Hs, ctrl, slot2tok);

  k_down<<<1792, 256, 0, stream>>>(
      Hx, Hs, (const short*)ewd, (const short*)swd, rout, out, ctrl);

  k_add<<<T_TOK, 256, 0, stream>>>(out, rout, tok_row, top_w);
}

// Round 6
// 678.963 us; speedup vs baseline: 1.3732x; 1.0794x over previous
//
#include <hip/hip_runtime.h>
#include <cstdint>
#include <cstddef>

#define T_TOK 2048
#define DHID  2048
#define NEXP  8
#define FMOE  1408
#define FSH   2816
#define CAP   5120   // 4096 slots + 8*127 per-expert padding fits

// counted vmcnt wait (T4) — literal N required
#define VMCNT(N) asm volatile("s_waitcnt vmcnt(" #N ")" ::: "memory")

typedef short short8 __attribute__((ext_vector_type(8)));
typedef short short4v __attribute__((ext_vector_type(4)));
typedef float f32x4  __attribute__((ext_vector_type(4)));

__device__ __forceinline__ float bf2f(short s) {
  unsigned u = ((unsigned)(unsigned short)s) << 16;
  return __builtin_bit_cast(float, u);
}
__device__ __forceinline__ short f2bf(float f) {
  unsigned u = __builtin_bit_cast(unsigned, f);
  u += 0x7fffu + ((u >> 16) & 1u);
  return (short)(u >> 16);
}
__device__ __forceinline__ short8 cvt8(float4 a, float4 b) {
  short8 r;
  r[0]=f2bf(a.x); r[1]=f2bf(a.y); r[2]=f2bf(a.z); r[3]=f2bf(a.w);
  r[4]=f2bf(b.x); r[5]=f2bf(b.y); r[6]=f2bf(b.z); r[7]=f2bf(b.w);
  return r;
}

__device__ __forceinline__ void gl_lds16(const void* g, void* l) {
  __builtin_amdgcn_global_load_lds(
      (const __attribute__((address_space(1))) void*)g,
      (__attribute__((address_space(3))) void*)l, 16, 0, 0);
}

// ---- in-place fp32 -> bf16 conversion ----
// Named v0/v1/v2 with compile-time-guarded lanes (len4 in {352,512,704}) —
// the old v[cnt++] runtime indexing allocated scratch (rule #20) and turned
// 230MB of conversion into private-memory HBM round-trips.
__global__ void k_cvt(float* __restrict__ swg, float* __restrict__ swu,
                      float* __restrict__ swd, float* __restrict__ ewg,
                      float* __restrict__ ewu, float* __restrict__ ewd)
{
  int id = blockIdx.x;
  float* base; int row, len;
  if      (id < 2816)  { base = swg; row = id;          len = 2048; }
  else if (id < 5632)  { base = swu; row = id - 2816;   len = 2048; }
  else if (id < 7680)  { base = swd; row = id - 5632;   len = 2816; }
  else if (id < 18944) { base = ewg; row = id - 7680;   len = 2048; }
  else if (id < 30208) { base = ewu; row = id - 18944;  len = 2048; }
  else                 { base = ewd; row = id - 30208;  len = 1408; }
  float* rp = base + (size_t)row * len;
  int t = threadIdx.x, len4 = len >> 2;
  const float4* rp4 = (const float4*)rp;
  bool g1 = (t + 256) < len4, g2 = (t + 512) < len4;
  float4 v0 = rp4[t];
  float4 v1 = {0.f,0.f,0.f,0.f}, v2 = {0.f,0.f,0.f,0.f};
  if (g1) v1 = rp4[t + 256];
  if (g2) v2 = rp4[t + 512];
  __syncthreads();
  short4v* sp = (short4v*)rp;
  {
    short4v s; s[0]=f2bf(v0.x); s[1]=f2bf(v0.y); s[2]=f2bf(v0.z); s[3]=f2bf(v0.w);
    sp[t] = s;
  }
  if (g1) {
    short4v s; s[0]=f2bf(v1.x); s[1]=f2bf(v1.y); s[2]=f2bf(v1.z); s[3]=f2bf(v1.w);
    sp[t + 256] = s;
  }
  if (g2) {
    short4v s; s[0]=f2bf(v2.x); s[1]=f2bf(v2.y); s[2]=f2bf(v2.z); s[3]=f2bf(v2.w);
    sp[t + 512] = s;
  }
}

// ---- gating: fp32 scores, sigmoid, top-2, counts; also write x as bf16 ----
__global__ void k_gate(const float* __restrict__ x, const float* __restrict__ gw,
                       int* __restrict__ top_idx, float* __restrict__ top_w,
                       int* __restrict__ ctrl, short* __restrict__ x16)
{
  int t = blockIdx.x, tid = threadIdx.x;
  const float* xr = x + (size_t)t * DHID + tid * 8;
  float4 v0 = *(const float4*)xr;
  float4 v1 = *(const float4*)(xr + 4);
  *(short8*)(x16 + (size_t)t * DHID + tid * 8) = cvt8(v0, v1);

  float s[NEXP];
  #pragma unroll
  for (int e = 0; e < NEXP; e++) {
    const float* gr = gw + e * DHID + tid * 8;
    float4 g0 = *(const float4*)gr;
    float4 g1 = *(const float4*)(gr + 4);
    s[e] = v0.x*g0.x + v0.y*g0.y + v0.z*g0.z + v0.w*g0.w
         + v1.x*g1.x + v1.y*g1.y + v1.z*g1.z + v1.w*g1.w;
  }
  #pragma unroll
  for (int e = 0; e < NEXP; e++)
    #pragma unroll
    for (int off = 32; off > 0; off >>= 1)
      s[e] += __shfl_xor(s[e], off);

  __shared__ float red[4][NEXP];
  int lane = tid & 63, wave = tid >> 6;
  if (lane == 0)
    for (int e = 0; e < NEXP; e++) red[wave][e] = s[e];
  __syncthreads();

  if (tid == 0) {
    float sc[NEXP];
    for (int e = 0; e < NEXP; e++) {
      float v = red[0][e] + red[1][e] + red[2][e] + red[3][e];
      sc[e] = 1.f / (1.f + __expf(-v));
    }
    int i0 = 0; float s0 = sc[0];
    for (int e = 1; e < NEXP; e++) if (sc[e] > s0) { s0 = sc[e]; i0 = e; }
    int i1 = -1; float s1 = -1e30f;
    for (int e = 0; e < NEXP; e++) if (e != i0 && sc[e] > s1) { s1 = sc[e]; i1 = e; }
    float inv = 2.5f / (s0 + s1 + 1e-20f);
    top_idx[2*t] = i0; top_idx[2*t+1] = i1;
    top_w[2*t] = s0 * inv; top_w[2*t+1] = s1 * inv;
    atomicAdd(&ctrl[i0], 1);
    atomicAdd(&ctrl[i1], 1);
  }
}

// ---- offsets + flat-work prefix tables (BN=64 tiles) ----
__global__ void k_offsets(int* __restrict__ ctrl)
{
  if (blockIdx.x == 0 && threadIdx.x == 0) {
    int cum = 0, gp = 0, dp = 0;
    ctrl[24] = 0; ctrl[40] = 0;
    for (int e = 0; e < NEXP; e++) {
      ctrl[16 + e] = cum;
      int mb = (ctrl[e] + 127) >> 7;
      cum += mb << 7;
      gp += mb * (FMOE / 64); ctrl[25 + e] = gp;
      dp += mb * (DHID / 64); ctrl[41 + e] = dp;
    }
    ctrl[33] = gp + (T_TOK / 128) * (FSH / 64);    // + shared 16*44
    ctrl[49] = dp + (T_TOK / 128) * (DHID / 64);   // + shared 16*32
  }
}

// ---- slot maps ----
__global__ void k_slotmap(const int* __restrict__ top_idx, int* __restrict__ ctrl,
                          int* __restrict__ tok_row, int* __restrict__ slot2tok)
{
  int i = blockIdx.x * 256 + threadIdx.x;
  if (i >= 2 * T_TOK) return;
  int e = top_idx[i];
  int slot = atomicAdd(&ctrl[8 + e], 1);
  int row = ctrl[16 + e] + slot;
  tok_row[i] = row;
  slot2tok[row] = i >> 1;
}

// ---- flat fused gate/up GEMM + SiLU, 128x64 tile ----
// 2-buffer counted-vmcnt pipeline (no drain): stage(t+1); vmcnt(4); barrier;
// compute(t); barrier. Loads issued at step t are waited at step t+1 ->
// per-step exposure ~(L+C)/2 instead of L. LDS unchanged (32KB), occupancy
// unchanged (r4 lesson: pipeline depth must not cost resident blocks).
__global__ __launch_bounds__(256, 4) void k_guf(
    const short* __restrict__ x16,
    const short* __restrict__ ewg, const short* __restrict__ ewu,
    const short* __restrict__ swg, const short* __restrict__ swu,
    short* __restrict__ Hx, short* __restrict__ Hs,
    const int* __restrict__ ctrl, const int* __restrict__ slot2tok)
{
  int W = ctrl[33];
  int b = blockIdx.x;
  if (b >= W) return;
  // bijective chunked XCD swizzle (m204)
  int cq = W >> 3, cr = W & 7, xcd = b & 7, li = b >> 3;
  int flat = (xcd < cr ? xcd * (cq + 1) : cr * (cq + 1) + (xcd - cr) * cq) + li;

  int z = 0;
  while (flat >= ctrl[25 + z]) z++;
  int w = flat - ctrl[24 + z];

  int tid = threadIdx.x;
  int r = tid >> 2, sl = (tid & 3) * 8;

  const short *Bg, *Bu; short* H; int N;
  int tokr0, tokr1; size_t hrow0;
  if (z == 8) {
    // m-fastest: consecutive blocks share the B panel
    int my = w & 15, nx = w >> 4;
    int n0v = nx * 64;
    N = FSH; H = Hs; Bg = swg + (size_t)n0v * (2 * DHID); Bu = swu + (size_t)n0v * (2 * DHID);
    int m0 = my * 128;
    tokr0 = m0 + r; tokr1 = m0 + r + 64;
    hrow0 = m0;
    w = n0v;
  } else {
    int mb = (ctrl[z] + 127) >> 7;
    int my = w % mb, nx = w / mb;
    int n0v = nx * 64;
    N = FMOE; H = Hx;
    size_t woff = (size_t)z * FMOE * (2 * DHID);
    Bg = ewg + woff + (size_t)n0v * (2 * DHID);
    Bu = ewu + woff + (size_t)n0v * (2 * DHID);
    int cnt = ctrl[z], base = ctrl[16 + z];
    int m0 = my * 128;
    int rr0 = m0 + r, rr1 = m0 + r + 64;
    tokr0 = (rr0 < cnt) ? slot2tok[base + rr0] : 0;
    tokr1 = (rr1 < cnt) ? slot2tok[base + rr1] : 0;
    hrow0 = base + m0;
    w = n0v;
  }
  int n0 = w;

  __shared__ short As [2][128 * 32];   // 16 KB
  __shared__ short Bgs[2][64 * 32];    //  8 KB
  __shared__ short Bus[2][64 * 32];    //  8 KB

  int lane = tid & 63, wave = tid >> 6;
  int l15 = lane & 15, qh = lane >> 4;
  int wm = (wave >> 1) * 64, wn = (wave & 1) * 32;

  f32x4 z4 = {0.f, 0.f, 0.f, 0.f};
  f32x4 accg[4][2], accu[4][2];
  #pragma unroll
  for (int a = 0; a < 4; a++)
    #pragma unroll
    for (int c = 0; c < 2; c++) { accg[a][c] = z4; accu[a][c] = z4; }

  const short* Ag0 = x16 + (size_t)tokr0 * DHID + sl;
  const short* Ag1 = x16 + (size_t)tokr1 * DHID + sl;
  const short* Bgp = Bg + (size_t)r * (2 * DHID) + sl;
  const short* Bup = Bu + (size_t)r * (2 * DHID) + sl;

  auto stage = [&](int bi, int k0) {
    gl_lds16(Ag0 + k0, &As [bi][tid * 8]);
    gl_lds16(Ag1 + k0, &As [bi][tid * 8 + 2048]);
    gl_lds16(Bgp + k0, &Bgs[bi][tid * 8]);
    gl_lds16(Bup + k0, &Bus[bi][tid * 8]);
  };
  auto compute = [&](int bi) {
    short8 af[4], bg[2], bu[2];
    #pragma unroll
    for (int mi = 0; mi < 4; mi++)
      af[mi] = *(const short8*)&As[bi][(wm + mi * 16 + l15) * 32 + qh * 8];
    #pragma unroll
    for (int ni = 0; ni < 2; ni++) {
      bg[ni] = *(const short8*)&Bgs[bi][(wn + ni * 16 + l15) * 32 + qh * 8];
      bu[ni] = *(const short8*)&Bus[bi][(wn + ni * 16 + l15) * 32 + qh * 8];
    }
    #pragma unroll
    for (int mi = 0; mi < 4; mi++)
      #pragma unroll
      for (int ni = 0; ni < 2; ni++) {
        accg[mi][ni] = __builtin_amdgcn_mfma_f32_16x16x32_bf16(af[mi], bg[ni], accg[mi][ni], 0, 0, 0);
        accu[mi][ni] = __builtin_amdgcn_mfma_f32_16x16x32_bf16(af[mi], bu[ni], accu[mi][ni], 0, 0, 0);
      }
  };

  stage(0, 0);
  VMCNT(0);
  __builtin_amdgcn_s_barrier();
  for (int t = 0; t < 64; ++t) {
    int cur = t & 1;
    if (t < 63) {
      stage(cur ^ 1, (t + 1) * 32);   // buf (t+1)&1: last read by compute(t-1), done before prev end-barrier
      VMCNT(4);                        // my stage(t) loads landed (4 outstanding = stage(t+1))
    } else {
      VMCNT(0);
    }
    __builtin_amdgcn_s_barrier();      // everyone's stage(t) landed
    compute(cur);
    __builtin_amdgcn_s_barrier();      // all done reading buf t&1 before next stage overwrites
  }

  // epilogue: D row = qh*4 + reg, col = l15  [measured m89/m91]
  #pragma unroll
  for (int mi = 0; mi < 4; mi++) {
    #pragma unroll
    for (int rg = 0; rg < 4; rg++) {
      size_t row = hrow0 + wm + mi * 16 + qh * 4 + rg;
      size_t baseo = row * (size_t)N + n0 + wn + l15;
      #pragma unroll
      for (int ni = 0; ni < 2; ni++) {
        float g = accg[mi][ni][rg];
        float u = accu[mi][ni][rg];
        H[baseo + ni * 16] = f2bf((g / (1.f + __expf(-g))) * u);
      }
    }
  }
}

// ---- flat down GEMM: C[*,2048] = H[*,K] @ Wd[2048,K]^T, 128x64 tile ----
__global__ __launch_bounds__(256, 4) void k_down(
    const short* __restrict__ Hx, const short* __restrict__ Hs,
    const short* __restrict__ ewd, const short* __restrict__ swd,
    short* __restrict__ rout, float* __restrict__ out,
    const int* __restrict__ ctrl)
{
  int W = ctrl[49];
  int b = blockIdx.x;
  if (b >= W) return;
  int cq = W >> 3, cr = W & 7, xcd = b & 7, li = b >> 3;
  int flat = (xcd < cr ? xcd * (cq + 1) : cr * (cq + 1) + (xcd - cr) * cq) + li;

  int z = 0;
  while (flat >= ctrl[41 + z]) z++;
  int w = flat - ctrl[40 + z];

  const short *A, *B; int K; size_t crow0;
  int my, n0;
  if (z == 8) {
    my = w & 15; n0 = (w >> 4) * 64;
    A = Hs + (size_t)(my * 128) * FSH; B = swd; K = FSH;
    crow0 = my * 128;
  } else {
    int mb = (ctrl[z] + 127) >> 7;
    my = w % mb; n0 = (w / mb) * 64;
    int base = ctrl[16 + z];
    A = Hx + (size_t)(base + my * 128) * FMOE;
    B = ewd + (size_t)z * DHID * (2 * FMOE); K = FMOE;
    crow0 = base + my * 128;
  }

  __shared__ short As[2][128 * 32];   // 16 KB
  __shared__ short Bs[2][64 * 32];    //  8 KB

  int tid = threadIdx.x;
  int lane = tid & 63, wave = tid >> 6;
  int l15 = lane & 15, qh = lane >> 4;
  int wm = (wave >> 1) * 64, wn = (wave & 1) * 32;

  f32x4 z4 = {0.f, 0.f, 0.f, 0.f};
  f32x4 acc[4][2];
  #pragma unroll
  for (int a = 0; a < 4; a++)
    #pragma unroll
    for (int c = 0; c < 2; c++) acc[a][c] = z4;

  int r = tid >> 2, sl = (tid & 3) * 8;
  const short* Ag0 = A + (size_t)r * K + sl;
  const short* Ag1 = Ag0 + (size_t)64 * K;
  const short* Bp  = B + (size_t)(n0 + r) * (2 * K) + sl;

  auto stage = [&](int bi, int k0) {
    gl_lds16(Ag0 + k0, &As[bi][tid * 8]);
    gl_lds16(Ag1 + k0, &As[bi][tid * 8 + 2048]);
    gl_lds16(Bp  + k0, &Bs[bi][tid * 8]);
  };
  auto compute = [&](int bi) {
    short8 af[4], bf[2];
    #pragma unroll
    for (int mi = 0; mi < 4; mi++)
      af[mi] = *(const short8*)&As[bi][(wm + mi * 16 + l15) * 32 + qh * 8];
    #pragma unroll
    for (int ni = 0; ni < 2; ni++)
      bf[ni] = *(const short8*)&Bs[bi][(wn + ni * 16 + l15) * 32 + qh * 8];
    #pragma unroll
    for (int mi = 0; mi < 4; mi++)
      #pragma unroll
      for (int ni = 0; ni < 2; ni++)
        acc[mi][ni] = __builtin_amdgcn_mfma_f32_16x16x32_bf16(af[mi], bf[ni], acc[mi][ni], 0, 0, 0);
  };

  int nt = K >> 5;          // 44 (expert) or 88 (shared)
  stage(0, 0);
  VMCNT(0);
  __builtin_amdgcn_s_barrier();
  for (int t = 0; t < nt; ++t) {
    int cur = t & 1;
    if (t < nt - 1) {
      stage(cur ^ 1, (t + 1) * 32);
      VMCNT(3);
    } else {
      VMCNT(0);
    }
    __builtin_amdgcn_s_barrier();
    compute(cur);
    __builtin_amdgcn_s_barrier();
  }

  #pragma unroll
  for (int mi = 0; mi < 4; mi++) {
    #pragma unroll
    for (int rg = 0; rg < 4; rg++) {
      size_t row = crow0 + wm + mi * 16 + qh * 4 + rg;
      size_t baseo = row * (size_t)DHID + n0 + wn + l15;
      #pragma unroll
      for (int ni = 0; ni < 2; ni++) {
        float v = acc[mi][ni][rg];
        if (z == 8) out[baseo + ni * 16] = v;
        else        rout[baseo + ni * 16] = f2bf(v);
      }
    }
  }
}

// ---- out += w0*routed[row0] + w1*routed[row1] ----
__global__ void k_add(float* __restrict__ out, const short* __restrict__ rout,
                      const int* __restrict__ tok_row, const float* __restrict__ top_w)
{
  int t = blockIdx.x, tid = threadIdx.x;
  int r0 = tok_row[2*t], r1 = tok_row[2*t+1];
  float w0 = top_w[2*t], w1 = top_w[2*t+1];
  size_t c = (size_t)tid * 8;
  short8 a = *(const short8*)(rout + (size_t)r0 * DHID + c);
  short8 b = *(const short8*)(rout + (size_t)r1 * DHID + c);
  float* o = out + (size_t)t * DHID + c;
  float4 o0 = *(float4*)o;
  float4 o1 = *(float4*)(o + 4);
  o0.x += w0*bf2f(a[0]) + w1*bf2f(b[0]);
  o0.y += w0*bf2f(a[1]) + w1*bf2f(b[1]);
  o0.z += w0*bf2f(a[2]) + w1*bf2f(b[2]);
  o0.w += w0*bf2f(a[3]) + w1*bf2f(b[3]);
  o1.x += w0*bf2f(a[4]) + w1*bf2f(b[4]);
  o1.y += w0*bf2f(a[5]) + w1*bf2f(b[5]);
  o1.z += w0*bf2f(a[6]) + w1*bf2f(b[6]);
  o1.w += w0*bf2f(a[7]) + w1*bf2f(b[7]);
  *(float4*)o = o0;
  *(float4*)(o + 4) = o1;
}

extern "C" void kernel_launch(void* const* d_in, const int* in_sizes, int n_in,
                              void* d_out, int out_size, void* d_ws, size_t ws_size,
                              hipStream_t stream)
{
  const float* x  = (const float*)d_in[0];
  const float* gw = (const float*)d_in[1];
  float* swg = (float*)d_in[2];
  float* swu = (float*)d_in[3];
  float* swd = (float*)d_in[4];
  float* ewg = (float*)d_in[5];
  float* ewu = (float*)d_in[6];
  float* ewd = (float*)d_in[7];
  float* out = (float*)d_out;

  char* p = (char*)d_ws;
  int*   ctrl     = (int*)p;   p += 256;
  int*   top_idx  = (int*)p;   p += T_TOK * 2 * sizeof(int);
  float* top_w    = (float*)p; p += T_TOK * 2 * sizeof(float);
  int*   tok_row  = (int*)p;   p += T_TOK * 2 * sizeof(int);
  int*   slot2tok = (int*)p;   p += CAP * sizeof(int);
  short* x16  = (short*)p;     p += (size_t)T_TOK * DHID * 2;
  short* Hx   = (short*)p;     p += (size_t)CAP * FMOE * 2;
  short* Hs   = (short*)p;     p += (size_t)T_TOK * FSH * 2;
  short* rout = (short*)p;     p += (size_t)CAP * DHID * 2;

  (void)hipMemsetAsync(ctrl, 0, 64, stream);

  k_gate<<<T_TOK, 256, 0, stream>>>(x, gw, top_idx, top_w, ctrl, x16);
  k_offsets<<<1, 64, 0, stream>>>(ctrl);
  k_slotmap<<<(2 * T_TOK + 255) / 256, 256, 0, stream>>>(top_idx, ctrl, tok_row, slot2tok);
  k_cvt<<<46592, 256, 0, stream>>>(swg, swu, swd, ewg, ewu, ewd);

  // worst-case grids: guf <= 40 m-tiles*22 + 16*44 = 1584; down <= 40*32 + 16*32 = 1792
  k_guf<<<1600, 256, 0, stream>>>(
      x16, (const short*)ewg, (const short*)ewu,
      (const short*)swg, (const short*)swu, Hx, Hs, ctrl, slot2tok);

  k_down<<<1792, 256, 0, stream>>>(
      Hx, Hs, (const short*)ewd, (const short*)swd, rout, out, ctrl);

  k_add<<<T_TOK, 256, 0, stream>>>(out, rout, tok_row, top_w);
}